// Round 4
// baseline (97.076 us; speedup 1.0000x reference)
//
#include <hip/hip_runtime.h>
#include <hip/hip_bf16.h>
#include <math.h>

#define DD     128
#define BROWS  128         // rows per block
#define NWAVE  4
#define TPB    (NWAVE*64)  // 256 threads
#define WROWS  32          // rows per wave = one 32x32 MFMA n-extent
#define XSTR   136         // bf16 elems per LDS row (272B, 16B-aligned)
#define MAXBLK 8192

typedef __attribute__((ext_vector_type(8)))  short bf16x8;
typedef __attribute__((ext_vector_type(16))) float f32x16;

// static device scratch (rewritten every launch -> deterministic)
// layout: [L][T][ks][mt][lane][8]  (L=layer, T=hi/lo, ks=k-step of 16, mt=32-feature tile)
__device__ __align__(16) unsigned short g_wfrag[2*2*8*4*64*8]; // 128 KB
__device__ __align__(16) float g_b1p[DD];
__device__ float g_m, g_invZ;
__device__ float g_pm[MAXBLK], g_ps[MAXBLK];

__device__ __forceinline__ unsigned short f2b(float x){
    union { __hip_bfloat16 b; unsigned short u; } c;
    c.b = __float2bfloat16(x);
    return c.u;
}
__device__ __forceinline__ float b2f(unsigned short u){
    union { __hip_bfloat16 b; unsigned short u; } c;
    c.u = u;
    return __bfloat162float(c.b);
}

// ---- prep: split W1(:,0:128), W2 into bf16 hi/lo in 32x32x16 A-frag order ----
// A-frag: lane l holds A[m = mt*32 + (l&31)][k = ks*16 + (l>>5)*8 + r], r=0..7
__global__ __launch_bounds__(256)
void k_wprep(const float* __restrict__ W1, const float* __restrict__ W2)
{
    const int t    = blockIdx.x*256 + threadIdx.x;   // 0..8191
    const int lane = t & 63;
    const int mt   = (t>>6) & 3;
    const int ks   = (t>>8) & 7;
    const int T    = (t>>11) & 1;                    // 0 = hi, 1 = lo
    const int L    = (t>>12) & 1;                    // 0 = layer1, 1 = layer2
    const int col  = mt*32 + (lane & 31);
    const int kb   = ks*16 + ((lane>>5) << 3);
    const float* src = L ? (W2 + (size_t)col*128 + kb) : (W1 + (size_t)col*256 + kb);
    unsigned short o[8];
    #pragma unroll
    for (int r = 0; r < 8; ++r){
        float x = src[r];
        unsigned short h = f2b(x);
        o[r] = T ? f2b(x - b2f(h)) : h;
    }
    ushort4* dst = (ushort4*)&g_wfrag[(size_t)t * 8];
    dst[0] = *(ushort4*)&o[0];
    dst[1] = *(ushort4*)&o[4];
}

// ---- prep: fold u_rep half of layer1 into bias (exact fp32) ----
__global__ __launch_bounds__(128)
void k_b1p(const float* __restrict__ W1, const float* __restrict__ b1,
           const float* __restrict__ u)
{
    const int c = threadIdx.x;
    float a = b1[c];
    for (int j = 0; j < 128; ++j) a = fmaf(W1[(size_t)c*256 + 128 + j], u[j], a);
    g_b1p[c] = a;
}

// One layer, 32x32x16 path. B-frags hoisted; A-frags double-buffered so the
// unrolled ks-loop is {issue A(ks+1) -> 12 MFMA(ks)} with loads in flight.
template<int TH>
__device__ __forceinline__ void mlp_layer(
    const unsigned short (&Xh)[BROWS*XSTR],
    const unsigned short (&Xl)[BROWS*XSTR],
    const float* __restrict__ bias,
    f32x16 (&acc)[4], int lane, int wrow0)
{
    const int hg = lane >> 5;

    // bias init: acc[mt][qq*4+j] corresponds to feature mt*32 + qq*8 + hg*4 + j
    #pragma unroll
    for (int mt = 0; mt < 4; ++mt){
        #pragma unroll
        for (int qq = 0; qq < 4; ++qq){
            const float4 bv = *(const float4*)&bias[mt*32 + qq*8 + (hg<<2)];
            acc[mt][qq*4+0] = bv.x; acc[mt][qq*4+1] = bv.y;
            acc[mt][qq*4+2] = bv.z; acc[mt][qq*4+3] = bv.w;
        }
    }

    // hoist all B fragments: lane holds X[row = wrow0+(l&31)][ks*16 + hg*8 .. +8)
    bf16x8 Bh[8], Bl[8];
    const int ra = wrow0 + (lane & 31);
    #pragma unroll
    for (int ks = 0; ks < 8; ++ks){
        const int koff = ks*16 + (hg<<3);
        Bh[ks] = *(const bf16x8*)&Xh[ra*XSTR + koff];
        Bl[ks] = *(const bf16x8*)&Xl[ra*XSTR + koff];
    }

    const bf16x8* wf = (const bf16x8*)g_wfrag;
    bf16x8 Ah[2][4], Al[2][4];
    #pragma unroll
    for (int mt = 0; mt < 4; ++mt){
        Ah[0][mt] = wf[(((TH  )*8 + 0)*4 + mt)*64 + lane];
        Al[0][mt] = wf[(((TH+1)*8 + 0)*4 + mt)*64 + lane];
    }
    #pragma unroll
    for (int ks = 0; ks < 8; ++ks){
        const int cur = ks & 1, nxt = cur ^ 1;
        if (ks < 7){
            #pragma unroll
            for (int mt = 0; mt < 4; ++mt){
                Ah[nxt][mt] = wf[(((TH  )*8 + (ks+1))*4 + mt)*64 + lane];
                Al[nxt][mt] = wf[(((TH+1)*8 + (ks+1))*4 + mt)*64 + lane];
            }
        }
        #pragma unroll
        for (int mt = 0; mt < 4; ++mt){
            acc[mt] = __builtin_amdgcn_mfma_f32_32x32x16_bf16(Ah[cur][mt], Bh[ks], acc[mt], 0,0,0);
            acc[mt] = __builtin_amdgcn_mfma_f32_32x32x16_bf16(Ah[cur][mt], Bl[ks], acc[mt], 0,0,0);
            acc[mt] = __builtin_amdgcn_mfma_f32_32x32x16_bf16(Al[cur][mt], Bh[ks], acc[mt], 0,0,0);
        }
    }
}

__global__ __launch_bounds__(TPB, 2)
void k_mlp(const float* __restrict__ node1,
           const float* __restrict__ b2,
           const float* __restrict__ W3,
           float* __restrict__ out, int n)
{
    __shared__ unsigned short Xh[BROWS*XSTR];   // 34816 B
    __shared__ unsigned short Xl[BROWS*XSTR];   // 34816 B
    __shared__ float Ss[BROWS];
    const int tid   = threadIdx.x;
    const int lane  = tid & 63;
    const int w     = __builtin_amdgcn_readfirstlane(tid >> 6);
    const int hg    = lane >> 5;
    const int wrow0 = w * WROWS;
    const int r0    = blockIdx.x * BROWS;

    // ---- stage x tile: 128 rows x 128 k, split to bf16 hi/lo in LDS ----
    #pragma unroll
    for (int i = 0; i < 16; ++i){
        int idx = i*TPB + tid;            // 0..4095 float4 slots (= row*32 + kq)
        int row = idx >> 5, kq = idx & 31;
        float4 v = {0.f, 0.f, 0.f, 0.f};
        if (r0 + row < n) v = reinterpret_cast<const float4*>(node1)[(size_t)(r0+row)*32 + kq];
        ushort4 hv, lv;
        hv.x = f2b(v.x); lv.x = f2b(v.x - b2f(hv.x));
        hv.y = f2b(v.y); lv.y = f2b(v.y - b2f(hv.y));
        hv.z = f2b(v.z); lv.z = f2b(v.z - b2f(hv.z));
        hv.w = f2b(v.w); lv.w = f2b(v.w - b2f(hv.w));
        *(ushort4*)&Xh[row*XSTR + kq*4] = hv;
        *(ushort4*)&Xl[row*XSTR + kq*4] = lv;
    }
    __syncthreads();

    f32x16 acc[4];

    // ---- layer 1 ----
    mlp_layer<0>(Xh, Xl, g_b1p, acc, lane, wrow0);

    // relu + bf16-split writeback: acc[mt][qq*4+j] -> feature mt*32+qq*8+hg*4+j
    // of row wrow0+(lane&31). Rows are wave-private -> no barrier.
    {
        const int row = wrow0 + (lane & 31);
        #pragma unroll
        for (int mt = 0; mt < 4; ++mt){
            #pragma unroll
            for (int qq = 0; qq < 4; ++qq){
                const int c = mt*32 + qq*8 + (hg<<2);
                ushort4 hv, lv;
                float v;
                v = fmaxf(acc[mt][qq*4+0], 0.f); hv.x = f2b(v); lv.x = f2b(v - b2f(hv.x));
                v = fmaxf(acc[mt][qq*4+1], 0.f); hv.y = f2b(v); lv.y = f2b(v - b2f(hv.y));
                v = fmaxf(acc[mt][qq*4+2], 0.f); hv.z = f2b(v); lv.z = f2b(v - b2f(hv.z));
                v = fmaxf(acc[mt][qq*4+3], 0.f); hv.w = f2b(v); lv.w = f2b(v - b2f(hv.w));
                *(ushort4*)&Xh[row*XSTR + c] = hv;
                *(ushort4*)&Xl[row*XSTR + c] = lv;
            }
        }
    }

    // ---- layer 2 ----
    mlp_layer<2>(Xh, Xl, b2, acc, lane, wrow0);

    // ---- layer 3: s[row] = sum_c relu(h2[c][row]) * W3[c]  (b3 cancels in softmax) ----
    float p = 0.f;
    #pragma unroll
    for (int mt = 0; mt < 4; ++mt){
        #pragma unroll
        for (int qq = 0; qq < 4; ++qq){
            const float4 wv = *(const float4*)&W3[mt*32 + qq*8 + (hg<<2)];
            p = fmaf(fmaxf(acc[mt][qq*4+0], 0.f), wv.x, p);
            p = fmaf(fmaxf(acc[mt][qq*4+1], 0.f), wv.y, p);
            p = fmaf(fmaxf(acc[mt][qq*4+2], 0.f), wv.z, p);
            p = fmaf(fmaxf(acc[mt][qq*4+3], 0.f), wv.w, p);
        }
    }
    p += __shfl_xor(p, 32);
    if (lane < 32) Ss[wrow0 + lane] = p;
    __syncthreads();

    // ---- per-64-row-group softmax stats + raw score output (waves 0,1) ----
    if (w < 2){
        const int rb = w*64 + lane;
        const int ra = r0 + rb;
        const bool va = ra < n;
        const float s = Ss[rb];
        if (va) out[ra] = s;
        float m = va ? s : -3.0e38f;
        #pragma unroll
        for (int off = 32; off > 0; off >>= 1) m = fmaxf(m, __shfl_xor(m, off));
        float e = va ? expf(s - m) : 0.f;
        #pragma unroll
        for (int off = 32; off > 0; off >>= 1) e += __shfl_xor(e, off);
        if (lane == 0){ g_pm[blockIdx.x*2 + w] = m; g_ps[blockIdx.x*2 + w] = e; }
    }
}

__global__ __launch_bounds__(1024)
void k_combine(int ng)
{
    __shared__ float red[17];
    const int tid = threadIdx.x, lane = tid & 63, wv = tid >> 6;

    float m = -3.0e38f;
    for (int i = tid; i < ng; i += 1024) m = fmaxf(m, g_pm[i]);
    #pragma unroll
    for (int off = 32; off > 0; off >>= 1) m = fmaxf(m, __shfl_xor(m, off));
    if (lane == 0) red[wv] = m;
    __syncthreads();
    if (tid < 64){
        float v = (lane < 16) ? red[lane] : -3.0e38f;
        #pragma unroll
        for (int off = 32; off > 0; off >>= 1) v = fmaxf(v, __shfl_xor(v, off));
        if (lane == 0) red[16] = v;
    }
    __syncthreads();
    m = red[16];

    float z = 0.f;
    for (int i = tid; i < ng; i += 1024) z += g_ps[i] * expf(g_pm[i] - m);
    #pragma unroll
    for (int off = 32; off > 0; off >>= 1) z += __shfl_xor(z, off);
    __syncthreads();
    if (lane == 0) red[wv] = z;
    __syncthreads();
    if (tid < 64){
        float v = (lane < 16) ? red[lane] : 0.f;
        #pragma unroll
        for (int off = 32; off > 0; off >>= 1) v += __shfl_xor(v, off);
        if (lane == 0){ g_m = m; g_invZ = 1.0f / v; }
    }
}

__global__ __launch_bounds__(256)
void k_norm(float* __restrict__ s, int n)
{
    const int i = blockIdx.x * 256 + threadIdx.x;
    const float m = g_m, r = g_invZ;
    const int n4 = n >> 2;
    if (i < n4){
        float4 v = reinterpret_cast<float4*>(s)[i];
        v.x = expf(v.x - m) * r;
        v.y = expf(v.y - m) * r;
        v.z = expf(v.z - m) * r;
        v.w = expf(v.w - m) * r;
        reinterpret_cast<float4*>(s)[i] = v;
    }
    const int rem = n - (n4 << 2);
    if (i < rem){
        int t = (n4 << 2) + i;
        s[t] = expf(s[t] - m) * r;
    }
}

extern "C" void kernel_launch(void* const* d_in, const int* in_sizes, int n_in,
                              void* d_out, int out_size, void* d_ws, size_t ws_size,
                              hipStream_t stream)
{
    const float* node1 = (const float*)d_in[0];
    const float* urep  = (const float*)d_in[1];
    const float* W1    = (const float*)d_in[3];
    const float* b1    = (const float*)d_in[4];
    const float* W2    = (const float*)d_in[5];
    const float* b2    = (const float*)d_in[6];
    const float* W3    = (const float*)d_in[7];
    float* out = (float*)d_out;

    const int n    = in_sizes[0] / DD;            // 200000
    const int nblk = (n + BROWS - 1) / BROWS;     // 1563
    const int ng   = nblk * 2;                    // 64-row stat groups

    k_wprep<<<dim3(32), dim3(256), 0, stream>>>(W1, W2);
    k_b1p<<<dim3(1), dim3(128), 0, stream>>>(W1, b1, urep);
    k_mlp<<<dim3(nblk), dim3(TPB), 0, stream>>>(node1, b2, W3, out, n);
    k_combine<<<dim3(1), dim3(1024), 0, stream>>>(ng);

    const int n4  = n >> 2;
    const int nb3 = (n4 + 255) / 256 > 0 ? (n4 + 255) / 256 : 1;
    k_norm<<<dim3(nb3), dim3(256), 0, stream>>>(out, n);
}

// Round 5
// 74.449 us; speedup vs baseline: 1.3039x; 1.3039x over previous
//
#include <hip/hip_runtime.h>
#include <hip/hip_bf16.h>
#include <math.h>

#define DD     128
#define BROWS  128         // rows per block
#define NWAVE  4
#define TPB    (NWAVE*64)  // 256 threads
#define WROWS  32
#define XSTR   136         // bf16 elems per LDS row (272B, 16B-aligned)
#define MAXBLK 8192

typedef __attribute__((ext_vector_type(8)))  short bf16x8;
typedef __attribute__((ext_vector_type(16))) float f32x16;

// static device scratch (rewritten every launch -> deterministic)
// layout: [L][T][ks][mt][lane][8]  (L=layer, T=hi/lo, ks=k-step of 16, mt=32-feature tile)
__device__ __align__(16) unsigned short g_wfrag[2*2*8*4*64*8]; // 128 KB
__device__ __align__(16) float g_b1p[DD];
__device__ float g_m, g_invZ;
__device__ float g_pm[MAXBLK], g_ps[MAXBLK];

__device__ __forceinline__ unsigned short f2b(float x){
    union { __hip_bfloat16 b; unsigned short u; } c;
    c.b = __float2bfloat16(x);
    return c.u;
}
__device__ __forceinline__ float b2f(unsigned short u){
    union { __hip_bfloat16 b; unsigned short u; } c;
    c.u = u;
    return __bfloat162float(c.b);
}

// ---- prep: split W1(:,0:128), W2 into bf16 hi/lo in 32x32x16 A-frag order ----
// A-frag: lane l holds A[m = mt*32 + (l&31)][k = ks*16 + (l>>5)*8 + r], r=0..7
__global__ __launch_bounds__(256)
void k_wprep(const float* __restrict__ W1, const float* __restrict__ W2)
{
    const int t    = blockIdx.x*256 + threadIdx.x;   // 0..8191
    const int lane = t & 63;
    const int mt   = (t>>6) & 3;
    const int ks   = (t>>8) & 7;
    const int T    = (t>>11) & 1;                    // 0 = hi, 1 = lo
    const int L    = (t>>12) & 1;                    // 0 = layer1, 1 = layer2
    const int col  = mt*32 + (lane & 31);
    const int kb   = ks*16 + ((lane>>5) << 3);
    const float* src = L ? (W2 + (size_t)col*128 + kb) : (W1 + (size_t)col*256 + kb);
    unsigned short o[8];
    #pragma unroll
    for (int r = 0; r < 8; ++r){
        float x = src[r];
        unsigned short h = f2b(x);
        o[r] = T ? f2b(x - b2f(h)) : h;
    }
    ushort4* dst = (ushort4*)&g_wfrag[(size_t)t * 8];
    dst[0] = *(ushort4*)&o[0];
    dst[1] = *(ushort4*)&o[4];
}

// ---- prep: fold u_rep half of layer1 into bias (exact fp32) ----
__global__ __launch_bounds__(128)
void k_b1p(const float* __restrict__ W1, const float* __restrict__ b1,
           const float* __restrict__ u)
{
    const int c = threadIdx.x;
    float a = b1[c];
    for (int j = 0; j < 128; ++j) a = fmaf(W1[(size_t)c*256 + 128 + j], u[j], a);
    g_b1p[c] = a;
}

// One layer, m-split: this wave's 32 features (mt = w) for all 128 rows.
// A is fully register-resident (16 frags); B streams from LDS.
__device__ __forceinline__ void layer_compute(
    const bf16x8 (&Ah)[8], const bf16x8 (&Al)[8],
    const unsigned short (&Xh)[BROWS*XSTR],
    const unsigned short (&Xl)[BROWS*XSTR],
    const float* __restrict__ bias,
    f32x16 (&acc)[4], int lane, int w)
{
    const int hg = lane >> 5;
    // bias init: acc[nt][qq*4+j] <-> feature w*32 + qq*8 + hg*4 + j, row nt*32+(l&31)
    #pragma unroll
    for (int qq = 0; qq < 4; ++qq){
        const float4 bv = *(const float4*)&bias[w*32 + qq*8 + (hg<<2)];
        #pragma unroll
        for (int nt = 0; nt < 4; ++nt){
            acc[nt][qq*4+0] = bv.x; acc[nt][qq*4+1] = bv.y;
            acc[nt][qq*4+2] = bv.z; acc[nt][qq*4+3] = bv.w;
        }
    }
    #pragma unroll
    for (int ks = 0; ks < 8; ++ks){
        const int koff = ks*16 + (hg<<3);
        #pragma unroll
        for (int nt = 0; nt < 4; ++nt){
            const int row = nt*32 + (lane & 31);
            const bf16x8 Bh = *(const bf16x8*)&Xh[row*XSTR + koff];
            const bf16x8 Bl = *(const bf16x8*)&Xl[row*XSTR + koff];
            acc[nt] = __builtin_amdgcn_mfma_f32_32x32x16_bf16(Ah[ks], Bh, acc[nt], 0,0,0);
            acc[nt] = __builtin_amdgcn_mfma_f32_32x32x16_bf16(Ah[ks], Bl, acc[nt], 0,0,0);
            acc[nt] = __builtin_amdgcn_mfma_f32_32x32x16_bf16(Al[ks], Bh, acc[nt], 0,0,0);
        }
    }
}

__global__ __launch_bounds__(TPB, 2)
void k_mlp(const float* __restrict__ node1,
           const float* __restrict__ b2,
           const float* __restrict__ W3,
           float* __restrict__ out, int n)
{
    __shared__ unsigned short Xh[BROWS*XSTR];   // 34816 B
    __shared__ unsigned short Xl[BROWS*XSTR];   // 34816 B
    __shared__ float Ps[NWAVE][BROWS];          // 2 KB layer-3 partials
    const int tid   = threadIdx.x;
    const int lane  = tid & 63;
    const int w     = __builtin_amdgcn_readfirstlane(tid >> 6);
    const int hg    = lane >> 5;
    const int r0    = blockIdx.x * BROWS;

    // ---- stage x tile: 128 rows x 128 k, split to bf16 hi/lo in LDS ----
    #pragma unroll
    for (int i = 0; i < 16; ++i){
        int idx = i*TPB + tid;            // 0..4095 float4 slots (= row*32 + kq)
        int row = idx >> 5, kq = idx & 31;
        float4 v = {0.f, 0.f, 0.f, 0.f};
        if (r0 + row < n) v = reinterpret_cast<const float4*>(node1)[(size_t)(r0+row)*32 + kq];
        ushort4 hv, lv;
        hv.x = f2b(v.x); lv.x = f2b(v.x - b2f(hv.x));
        hv.y = f2b(v.y); lv.y = f2b(v.y - b2f(hv.y));
        hv.z = f2b(v.z); lv.z = f2b(v.z - b2f(hv.z));
        hv.w = f2b(v.w); lv.w = f2b(v.w - b2f(hv.w));
        *(ushort4*)&Xh[row*XSTR + kq*4] = hv;
        *(ushort4*)&Xl[row*XSTR + kq*4] = lv;
    }

    const bf16x8* wf = (const bf16x8*)g_wfrag;

    // ---- A-frags for layer 1 (this wave's feature slice), issued before barrier ----
    bf16x8 A1h[8], A1l[8];
    #pragma unroll
    for (int ks = 0; ks < 8; ++ks){
        A1h[ks] = wf[((0*8 + ks)*4 + w)*64 + lane];   // L=0,T=hi
        A1l[ks] = wf[((1*8 + ks)*4 + w)*64 + lane];   // L=0,T=lo
    }
    __syncthreads();

    f32x16 acc[4];

    // ---- layer 1 ----
    layer_compute(A1h, A1l, Xh, Xl, g_b1p, acc, lane, w);

    // ---- A-frags for layer 2: issue now so they drain under barrier+writeback ----
    bf16x8 A2h[8], A2l[8];
    #pragma unroll
    for (int ks = 0; ks < 8; ++ks){
        A2h[ks] = wf[((2*8 + ks)*4 + w)*64 + lane];   // L=1,T=hi
        A2l[ks] = wf[((3*8 + ks)*4 + w)*64 + lane];   // L=1,T=lo
    }

    __syncthreads();   // everyone done READING X

    // relu + bf16-split writeback: wave w writes features [32w,32w+32) for all rows
    #pragma unroll
    for (int nt = 0; nt < 4; ++nt){
        const int row = nt*32 + (lane & 31);
        #pragma unroll
        for (int qq = 0; qq < 4; ++qq){
            const int c = w*32 + qq*8 + (hg<<2);
            ushort4 hv, lv;
            float v;
            v = fmaxf(acc[nt][qq*4+0], 0.f); hv.x = f2b(v); lv.x = f2b(v - b2f(hv.x));
            v = fmaxf(acc[nt][qq*4+1], 0.f); hv.y = f2b(v); lv.y = f2b(v - b2f(hv.y));
            v = fmaxf(acc[nt][qq*4+2], 0.f); hv.z = f2b(v); lv.z = f2b(v - b2f(hv.z));
            v = fmaxf(acc[nt][qq*4+3], 0.f); hv.w = f2b(v); lv.w = f2b(v - b2f(hv.w));
            *(ushort4*)&Xh[row*XSTR + c] = hv;
            *(ushort4*)&Xl[row*XSTR + c] = lv;
        }
    }
    __syncthreads();   // h1 fully written

    // ---- layer 2 ----
    layer_compute(A2h, A2l, Xh, Xl, b2, acc, lane, w);

    // ---- layer 3: per-wave partial over its 32 features ----
    float p[4] = {0.f, 0.f, 0.f, 0.f};
    #pragma unroll
    for (int qq = 0; qq < 4; ++qq){
        const float4 wv = *(const float4*)&W3[w*32 + qq*8 + (hg<<2)];
        #pragma unroll
        for (int nt = 0; nt < 4; ++nt){
            p[nt] = fmaf(fmaxf(acc[nt][qq*4+0], 0.f), wv.x, p[nt]);
            p[nt] = fmaf(fmaxf(acc[nt][qq*4+1], 0.f), wv.y, p[nt]);
            p[nt] = fmaf(fmaxf(acc[nt][qq*4+2], 0.f), wv.z, p[nt]);
            p[nt] = fmaf(fmaxf(acc[nt][qq*4+3], 0.f), wv.w, p[nt]);
        }
    }
    #pragma unroll
    for (int nt = 0; nt < 4; ++nt){
        p[nt] += __shfl_xor(p[nt], 32);
        if (lane < 32) Ps[w][nt*32 + lane] = p[nt];
    }
    __syncthreads();

    // ---- cross-wave feature reduction + per-64-row softmax stats (waves 0,1) ----
    if (w < 2){
        const int rb = w*64 + lane;
        const int ra = r0 + rb;
        const bool va = ra < n;
        const float s = Ps[0][rb] + Ps[1][rb] + Ps[2][rb] + Ps[3][rb];
        if (va) out[ra] = s;
        float m = va ? s : -3.0e38f;
        #pragma unroll
        for (int off = 32; off > 0; off >>= 1) m = fmaxf(m, __shfl_xor(m, off));
        float e = va ? expf(s - m) : 0.f;
        #pragma unroll
        for (int off = 32; off > 0; off >>= 1) e += __shfl_xor(e, off);
        if (lane == 0){ g_pm[blockIdx.x*2 + w] = m; g_ps[blockIdx.x*2 + w] = e; }
    }
}

__global__ __launch_bounds__(1024)
void k_combine(int ng)
{
    __shared__ float red[17];
    const int tid = threadIdx.x, lane = tid & 63, wv = tid >> 6;

    float m = -3.0e38f;
    for (int i = tid; i < ng; i += 1024) m = fmaxf(m, g_pm[i]);
    #pragma unroll
    for (int off = 32; off > 0; off >>= 1) m = fmaxf(m, __shfl_xor(m, off));
    if (lane == 0) red[wv] = m;
    __syncthreads();
    if (tid < 64){
        float v = (lane < 16) ? red[lane] : -3.0e38f;
        #pragma unroll
        for (int off = 32; off > 0; off >>= 1) v = fmaxf(v, __shfl_xor(v, off));
        if (lane == 0) red[16] = v;
    }
    __syncthreads();
    m = red[16];

    float z = 0.f;
    for (int i = tid; i < ng; i += 1024) z += g_ps[i] * expf(g_pm[i] - m);
    #pragma unroll
    for (int off = 32; off > 0; off >>= 1) z += __shfl_xor(z, off);
    __syncthreads();
    if (lane == 0) red[wv] = z;
    __syncthreads();
    if (tid < 64){
        float v = (lane < 16) ? red[lane] : 0.f;
        #pragma unroll
        for (int off = 32; off > 0; off >>= 1) v += __shfl_xor(v, off);
        if (lane == 0){ g_m = m; g_invZ = 1.0f / v; }
    }
}

__global__ __launch_bounds__(256)
void k_norm(float* __restrict__ s, int n)
{
    const int i = blockIdx.x * 256 + threadIdx.x;
    const float m = g_m, r = g_invZ;
    const int n4 = n >> 2;
    if (i < n4){
        float4 v = reinterpret_cast<float4*>(s)[i];
        v.x = expf(v.x - m) * r;
        v.y = expf(v.y - m) * r;
        v.z = expf(v.z - m) * r;
        v.w = expf(v.w - m) * r;
        reinterpret_cast<float4*>(s)[i] = v;
    }
    const int rem = n - (n4 << 2);
    if (i < rem){
        int t = (n4 << 2) + i;
        s[t] = expf(s[t] - m) * r;
    }
}

extern "C" void kernel_launch(void* const* d_in, const int* in_sizes, int n_in,
                              void* d_out, int out_size, void* d_ws, size_t ws_size,
                              hipStream_t stream)
{
    const float* node1 = (const float*)d_in[0];
    const float* urep  = (const float*)d_in[1];
    const float* W1    = (const float*)d_in[3];
    const float* b1    = (const float*)d_in[4];
    const float* W2    = (const float*)d_in[5];
    const float* b2    = (const float*)d_in[6];
    const float* W3    = (const float*)d_in[7];
    float* out = (float*)d_out;

    const int n    = in_sizes[0] / DD;            // 200000
    const int nblk = (n + BROWS - 1) / BROWS;     // 1563
    const int ng   = nblk * 2;                    // 64-row stat groups

    k_wprep<<<dim3(32), dim3(256), 0, stream>>>(W1, W2);
    k_b1p<<<dim3(1), dim3(128), 0, stream>>>(W1, b1, urep);
    k_mlp<<<dim3(nblk), dim3(TPB), 0, stream>>>(node1, b2, W3, out, n);
    k_combine<<<dim3(1), dim3(1024), 0, stream>>>(ng);

    const int n4  = n >> 2;
    const int nb3 = (n4 + 255) / 256 > 0 ? (n4 + 255) / 256 : 1;
    k_norm<<<dim3(nb3), dim3(256), 0, stream>>>(out, n);
}

// Round 6
// 65.958 us; speedup vs baseline: 1.4718x; 1.1287x over previous
//
#include <hip/hip_runtime.h>
#include <hip/hip_bf16.h>
#include <math.h>

#define DD     128
#define BROWS  64          // rows per block
#define NWAVE  4
#define TPB    (NWAVE*64)  // 256 threads
#define XSTR   136         // bf16 elems per LDS row (272B, 16B-aligned)
#define MAXBLK 8192

typedef __attribute__((ext_vector_type(8)))  short bf16x8;
typedef __attribute__((ext_vector_type(16))) float f32x16;

// static device scratch (rewritten every launch -> deterministic)
// layout: [L][T][ks][mt][lane][8]  (L=layer, T=hi/lo, ks=k-step of 16, mt=32-feature tile)
__device__ __align__(16) unsigned short g_wfrag[2*2*8*4*64*8]; // 128 KB
__device__ __align__(16) float g_b1p[DD];
__device__ float g_m, g_invZ;
__device__ float g_pm[MAXBLK], g_ps[MAXBLK];

__device__ __forceinline__ unsigned short f2b(float x){
    union { __hip_bfloat16 b; unsigned short u; } c;
    c.b = __float2bfloat16(x);
    return c.u;
}
__device__ __forceinline__ float b2f(unsigned short u){
    union { __hip_bfloat16 b; unsigned short u; } c;
    c.u = u;
    return __bfloat162float(c.b);
}

// ---- prep: split W1(:,0:128), W2 into bf16 hi/lo in 32x32x16 A-frag order ----
// A-frag: lane l holds A[m = mt*32 + (l&31)][k = ks*16 + (l>>5)*8 + r], r=0..7
__global__ __launch_bounds__(256)
void k_wprep(const float* __restrict__ W1, const float* __restrict__ W2)
{
    const int t    = blockIdx.x*256 + threadIdx.x;   // 0..8191
    const int lane = t & 63;
    const int mt   = (t>>6) & 3;
    const int ks   = (t>>8) & 7;
    const int T    = (t>>11) & 1;                    // 0 = hi, 1 = lo
    const int L    = (t>>12) & 1;                    // 0 = layer1, 1 = layer2
    const int col  = mt*32 + (lane & 31);
    const int kb   = ks*16 + ((lane>>5) << 3);
    const float* src = L ? (W2 + (size_t)col*128 + kb) : (W1 + (size_t)col*256 + kb);
    unsigned short o[8];
    #pragma unroll
    for (int r = 0; r < 8; ++r){
        float x = src[r];
        unsigned short h = f2b(x);
        o[r] = T ? f2b(x - b2f(h)) : h;
    }
    ushort4* dst = (ushort4*)&g_wfrag[(size_t)t * 8];
    dst[0] = *(ushort4*)&o[0];
    dst[1] = *(ushort4*)&o[4];
}

// ---- prep: fold u_rep half of layer1 into bias (exact fp32) ----
__global__ __launch_bounds__(128)
void k_b1p(const float* __restrict__ W1, const float* __restrict__ b1,
           const float* __restrict__ u)
{
    const int c = threadIdx.x;
    float a = b1[c];
    for (int j = 0; j < 128; ++j) a = fmaf(W1[(size_t)c*256 + 128 + j], u[j], a);
    g_b1p[c] = a;
}

// One layer, m-split: this wave's 32 features (mt = w) for all 64 rows.
// A register-resident (16 frags); B streams from LDS.
__device__ __forceinline__ void layer_compute(
    const bf16x8 (&Ah)[8], const bf16x8 (&Al)[8],
    const unsigned short (&Xh)[BROWS*XSTR],
    const unsigned short (&Xl)[BROWS*XSTR],
    const float* __restrict__ bias,
    f32x16 (&acc)[2], int lane, int w)
{
    const int hg = lane >> 5;
    // bias init: acc[nt][qq*4+j] <-> feature w*32 + qq*8 + hg*4 + j, row nt*32+(l&31)
    #pragma unroll
    for (int qq = 0; qq < 4; ++qq){
        const float4 bv = *(const float4*)&bias[w*32 + qq*8 + (hg<<2)];
        #pragma unroll
        for (int nt = 0; nt < 2; ++nt){
            acc[nt][qq*4+0] = bv.x; acc[nt][qq*4+1] = bv.y;
            acc[nt][qq*4+2] = bv.z; acc[nt][qq*4+3] = bv.w;
        }
    }
    #pragma unroll
    for (int ks = 0; ks < 8; ++ks){
        const int koff = ks*16 + (hg<<3);
        #pragma unroll
        for (int nt = 0; nt < 2; ++nt){
            const int row = nt*32 + (lane & 31);
            const bf16x8 Bh = *(const bf16x8*)&Xh[row*XSTR + koff];
            const bf16x8 Bl = *(const bf16x8*)&Xl[row*XSTR + koff];
            acc[nt] = __builtin_amdgcn_mfma_f32_32x32x16_bf16(Ah[ks], Bh, acc[nt], 0,0,0);
            acc[nt] = __builtin_amdgcn_mfma_f32_32x32x16_bf16(Ah[ks], Bl, acc[nt], 0,0,0);
            acc[nt] = __builtin_amdgcn_mfma_f32_32x32x16_bf16(Al[ks], Bh, acc[nt], 0,0,0);
        }
    }
}

__global__ __launch_bounds__(TPB, 4)
void k_mlp(const float* __restrict__ node1,
           const float* __restrict__ b2,
           const float* __restrict__ W3,
           float* __restrict__ out, int n)
{
    __shared__ unsigned short Xh[BROWS*XSTR];   // 17408 B
    __shared__ unsigned short Xl[BROWS*XSTR];   // 17408 B
    __shared__ float Ps[NWAVE][BROWS];          // 1 KB layer-3 partials
    const int tid   = threadIdx.x;
    const int lane  = tid & 63;
    const int w     = __builtin_amdgcn_readfirstlane(tid >> 6);
    const int hg    = lane >> 5;
    const int r0    = blockIdx.x * BROWS;

    // ---- stage x tile: 64 rows x 128 k, split to bf16 hi/lo in LDS ----
    #pragma unroll
    for (int i = 0; i < 8; ++i){
        int idx = i*TPB + tid;            // 0..2047 float4 slots (= row*32 + kq)
        int row = idx >> 5, kq = idx & 31;
        float4 v = {0.f, 0.f, 0.f, 0.f};
        if (r0 + row < n) v = reinterpret_cast<const float4*>(node1)[(size_t)(r0+row)*32 + kq];
        ushort4 hv, lv;
        hv.x = f2b(v.x); lv.x = f2b(v.x - b2f(hv.x));
        hv.y = f2b(v.y); lv.y = f2b(v.y - b2f(hv.y));
        hv.z = f2b(v.z); lv.z = f2b(v.z - b2f(hv.z));
        hv.w = f2b(v.w); lv.w = f2b(v.w - b2f(hv.w));
        *(ushort4*)&Xh[row*XSTR + kq*4] = hv;
        *(ushort4*)&Xl[row*XSTR + kq*4] = lv;
    }

    const bf16x8* wf = (const bf16x8*)g_wfrag;

    // ---- A-frags for layer 1 (this wave's feature slice), issued before barrier ----
    bf16x8 A1h[8], A1l[8];
    #pragma unroll
    for (int ks = 0; ks < 8; ++ks){
        A1h[ks] = wf[((0*8 + ks)*4 + w)*64 + lane];   // L=0,T=hi
        A1l[ks] = wf[((1*8 + ks)*4 + w)*64 + lane];   // L=0,T=lo
    }
    __syncthreads();

    f32x16 acc[2];

    // ---- layer 1 ----
    layer_compute(A1h, A1l, Xh, Xl, g_b1p, acc, lane, w);

    // ---- A-frags for layer 2: issue now so they drain under barrier+writeback ----
    bf16x8 A2h[8], A2l[8];
    #pragma unroll
    for (int ks = 0; ks < 8; ++ks){
        A2h[ks] = wf[((2*8 + ks)*4 + w)*64 + lane];   // L=1,T=hi
        A2l[ks] = wf[((3*8 + ks)*4 + w)*64 + lane];   // L=1,T=lo
    }

    __syncthreads();   // everyone done READING X

    // relu + bf16-split writeback: wave w writes features [32w,32w+32) for all rows
    #pragma unroll
    for (int nt = 0; nt < 2; ++nt){
        const int row = nt*32 + (lane & 31);
        #pragma unroll
        for (int qq = 0; qq < 4; ++qq){
            const int c = w*32 + qq*8 + (hg<<2);
            ushort4 hv, lv;
            float v;
            v = fmaxf(acc[nt][qq*4+0], 0.f); hv.x = f2b(v); lv.x = f2b(v - b2f(hv.x));
            v = fmaxf(acc[nt][qq*4+1], 0.f); hv.y = f2b(v); lv.y = f2b(v - b2f(hv.y));
            v = fmaxf(acc[nt][qq*4+2], 0.f); hv.z = f2b(v); lv.z = f2b(v - b2f(hv.z));
            v = fmaxf(acc[nt][qq*4+3], 0.f); hv.w = f2b(v); lv.w = f2b(v - b2f(hv.w));
            *(ushort4*)&Xh[row*XSTR + c] = hv;
            *(ushort4*)&Xl[row*XSTR + c] = lv;
        }
    }
    __syncthreads();   // h1 fully written

    // ---- layer 2 ----
    layer_compute(A2h, A2l, Xh, Xl, b2, acc, lane, w);

    // ---- layer 3: per-wave partial over its 32 features ----
    float p[2] = {0.f, 0.f};
    #pragma unroll
    for (int qq = 0; qq < 4; ++qq){
        const float4 wv = *(const float4*)&W3[w*32 + qq*8 + (hg<<2)];
        #pragma unroll
        for (int nt = 0; nt < 2; ++nt){
            p[nt] = fmaf(fmaxf(acc[nt][qq*4+0], 0.f), wv.x, p[nt]);
            p[nt] = fmaf(fmaxf(acc[nt][qq*4+1], 0.f), wv.y, p[nt]);
            p[nt] = fmaf(fmaxf(acc[nt][qq*4+2], 0.f), wv.z, p[nt]);
            p[nt] = fmaf(fmaxf(acc[nt][qq*4+3], 0.f), wv.w, p[nt]);
        }
    }
    #pragma unroll
    for (int nt = 0; nt < 2; ++nt){
        p[nt] += __shfl_xor(p[nt], 32);
        if (lane < 32) Ps[w][nt*32 + lane] = p[nt];
    }
    __syncthreads();

    // ---- cross-wave feature reduction + per-block softmax stats (wave 0) ----
    if (w == 0){
        const int ra = r0 + lane;
        const bool va = ra < n;
        const float s = Ps[0][lane] + Ps[1][lane] + Ps[2][lane] + Ps[3][lane];
        if (va) out[ra] = s;
        float m = va ? s : -3.0e38f;
        #pragma unroll
        for (int off = 32; off > 0; off >>= 1) m = fmaxf(m, __shfl_xor(m, off));
        float e = va ? expf(s - m) : 0.f;
        #pragma unroll
        for (int off = 32; off > 0; off >>= 1) e += __shfl_xor(e, off);
        if (lane == 0){ g_pm[blockIdx.x] = m; g_ps[blockIdx.x] = e; }
    }
}

__global__ __launch_bounds__(1024)
void k_combine(int ng)
{
    __shared__ float red[17];
    const int tid = threadIdx.x, lane = tid & 63, wv = tid >> 6;

    float m = -3.0e38f;
    for (int i = tid; i < ng; i += 1024) m = fmaxf(m, g_pm[i]);
    #pragma unroll
    for (int off = 32; off > 0; off >>= 1) m = fmaxf(m, __shfl_xor(m, off));
    if (lane == 0) red[wv] = m;
    __syncthreads();
    if (tid < 64){
        float v = (lane < 16) ? red[lane] : -3.0e38f;
        #pragma unroll
        for (int off = 32; off > 0; off >>= 1) v = fmaxf(v, __shfl_xor(v, off));
        if (lane == 0) red[16] = v;
    }
    __syncthreads();
    m = red[16];

    float z = 0.f;
    for (int i = tid; i < ng; i += 1024) z += g_ps[i] * expf(g_pm[i] - m);
    #pragma unroll
    for (int off = 32; off > 0; off >>= 1) z += __shfl_xor(z, off);
    __syncthreads();
    if (lane == 0) red[wv] = z;
    __syncthreads();
    if (tid < 64){
        float v = (lane < 16) ? red[lane] : 0.f;
        #pragma unroll
        for (int off = 32; off > 0; off >>= 1) v += __shfl_xor(v, off);
        if (lane == 0){ g_m = m; g_invZ = 1.0f / v; }
    }
}

__global__ __launch_bounds__(256)
void k_norm(float* __restrict__ s, int n)
{
    const int i = blockIdx.x * 256 + threadIdx.x;
    const float m = g_m, r = g_invZ;
    const int n4 = n >> 2;
    if (i < n4){
        float4 v = reinterpret_cast<float4*>(s)[i];
        v.x = expf(v.x - m) * r;
        v.y = expf(v.y - m) * r;
        v.z = expf(v.z - m) * r;
        v.w = expf(v.w - m) * r;
        reinterpret_cast<float4*>(s)[i] = v;
    }
    const int rem = n - (n4 << 2);
    if (i < rem){
        int t = (n4 << 2) + i;
        s[t] = expf(s[t] - m) * r;
    }
}

extern "C" void kernel_launch(void* const* d_in, const int* in_sizes, int n_in,
                              void* d_out, int out_size, void* d_ws, size_t ws_size,
                              hipStream_t stream)
{
    const float* node1 = (const float*)d_in[0];
    const float* urep  = (const float*)d_in[1];
    const float* W1    = (const float*)d_in[3];
    const float* b1    = (const float*)d_in[4];
    const float* W2    = (const float*)d_in[5];
    const float* b2    = (const float*)d_in[6];
    const float* W3    = (const float*)d_in[7];
    float* out = (float*)d_out;

    const int n    = in_sizes[0] / DD;            // 200000
    const int nblk = (n + BROWS - 1) / BROWS;     // 3125
    const int ng   = nblk;

    k_wprep<<<dim3(32), dim3(256), 0, stream>>>(W1, W2);
    k_b1p<<<dim3(1), dim3(128), 0, stream>>>(W1, b1, urep);
    k_mlp<<<dim3(nblk), dim3(TPB), 0, stream>>>(node1, b2, W3, out, n);
    k_combine<<<dim3(1), dim3(1024), 0, stream>>>(ng);

    const int n4  = n >> 2;
    const int nb3 = (n4 + 255) / 256 > 0 ? (n4 + 255) / 256 : 1;
    k_norm<<<dim3(nb3), dim3(256), 0, stream>>>(out, n);
}

// Round 7
// 65.535 us; speedup vs baseline: 1.4813x; 1.0065x over previous
//
#include <hip/hip_runtime.h>
#include <hip/hip_bf16.h>
#include <math.h>

#define DD     128
#define BROWS  64          // rows per block
#define NWAVE  4
#define TPB    (NWAVE*64)  // 256 threads
#define XSTR   136         // bf16 elems per LDS row (272B, 16B-aligned)
#define MAXBLK 8192

typedef __attribute__((ext_vector_type(8)))  short bf16x8;
typedef __attribute__((ext_vector_type(16))) float f32x16;

// static device scratch (rewritten every launch -> deterministic)
// layout: [L][T][ks][mt][lane][8]  (L=layer, T=hi/lo, ks=k-step of 16, mt=32-feature tile)
__device__ __align__(16) unsigned short g_wfrag[2*2*8*4*64*8]; // 128 KB
__device__ __align__(16) float g_b1p[DD];
__device__ float g_m, g_invZ;
__device__ float g_pm[MAXBLK], g_ps[MAXBLK];

__device__ __forceinline__ unsigned short f2b(float x){
    union { __hip_bfloat16 b; unsigned short u; } c;
    c.b = __float2bfloat16(x);
    return c.u;
}

// truncation-hi split: hi = upper 16 bits of f32 (exact float = bits&0xFFFF0000),
// lo = RNE-bf16(x - hi). |lo| <= 2^-8|x|, residual after lo-round <= 2^-17|x|.
__device__ __forceinline__ void split2(float x, unsigned short& h, unsigned short& l){
    unsigned int bx = __float_as_uint(x);
    float hf = __uint_as_float(bx & 0xFFFF0000u);
    h = (unsigned short)(bx >> 16);
    l = f2b(x - hf);
}

// ---- prep: split W1(:,0:128), W2 into bf16 hi/lo in 32x32x16 A-frag order ----
// A-frag: lane l holds A[m = mt*32 + (l&31)][k = ks*16 + (l>>5)*8 + r], r=0..7
__global__ __launch_bounds__(256)
void k_wprep(const float* __restrict__ W1, const float* __restrict__ W2)
{
    const int t    = blockIdx.x*256 + threadIdx.x;   // 0..8191
    const int lane = t & 63;
    const int mt   = (t>>6) & 3;
    const int ks   = (t>>8) & 7;
    const int T    = (t>>11) & 1;                    // 0 = hi, 1 = lo
    const int L    = (t>>12) & 1;                    // 0 = layer1, 1 = layer2
    const int col  = mt*32 + (lane & 31);
    const int kb   = ks*16 + ((lane>>5) << 3);
    const float* src = L ? (W2 + (size_t)col*128 + kb) : (W1 + (size_t)col*256 + kb);
    unsigned short o[8];
    #pragma unroll
    for (int r = 0; r < 8; ++r){
        float x = src[r];
        unsigned short h, l;
        split2(x, h, l);
        o[r] = T ? l : h;
    }
    ushort4* dst = (ushort4*)&g_wfrag[(size_t)t * 8];
    dst[0] = *(ushort4*)&o[0];
    dst[1] = *(ushort4*)&o[4];
}

// ---- prep: fold u_rep half of layer1 into bias (exact fp32) ----
__global__ __launch_bounds__(128)
void k_b1p(const float* __restrict__ W1, const float* __restrict__ b1,
           const float* __restrict__ u)
{
    const int c = threadIdx.x;
    float a = b1[c];
    for (int j = 0; j < 128; ++j) a = fmaf(W1[(size_t)c*256 + 128 + j], u[j], a);
    g_b1p[c] = a;
}

// One layer, m-split: this wave's 32 features (mt = w) for all 64 rows.
// A register-resident (pinned); B streams from LDS.
__device__ __forceinline__ void layer_compute(
    const bf16x8 (&Ah)[8], const bf16x8 (&Al)[8],
    const unsigned short (&Xh)[BROWS*XSTR],
    const unsigned short (&Xl)[BROWS*XSTR],
    const float* __restrict__ bias,
    f32x16 (&acc)[2], int lane, int w)
{
    const int hg = lane >> 5;
    #pragma unroll
    for (int qq = 0; qq < 4; ++qq){
        const float4 bv = *(const float4*)&bias[w*32 + qq*8 + (hg<<2)];
        #pragma unroll
        for (int nt = 0; nt < 2; ++nt){
            acc[nt][qq*4+0] = bv.x; acc[nt][qq*4+1] = bv.y;
            acc[nt][qq*4+2] = bv.z; acc[nt][qq*4+3] = bv.w;
        }
    }
    #pragma unroll
    for (int ks = 0; ks < 8; ++ks){
        const int koff = ks*16 + (hg<<3);
        #pragma unroll
        for (int nt = 0; nt < 2; ++nt){
            const int row = nt*32 + (lane & 31);
            const bf16x8 Bh = *(const bf16x8*)&Xh[row*XSTR + koff];
            const bf16x8 Bl = *(const bf16x8*)&Xl[row*XSTR + koff];
            acc[nt] = __builtin_amdgcn_mfma_f32_32x32x16_bf16(Ah[ks], Bh, acc[nt], 0,0,0);
            acc[nt] = __builtin_amdgcn_mfma_f32_32x32x16_bf16(Ah[ks], Bl, acc[nt], 0,0,0);
            acc[nt] = __builtin_amdgcn_mfma_f32_32x32x16_bf16(Al[ks], Bh, acc[nt], 0,0,0);
        }
    }
}

__global__ __launch_bounds__(TPB, 4)
void k_mlp(const float* __restrict__ node1,
           const float* __restrict__ b2,
           const float* __restrict__ W3,
           float* __restrict__ out, int n)
{
    __shared__ unsigned short Xh[BROWS*XSTR];   // 17408 B
    __shared__ unsigned short Xl[BROWS*XSTR];   // 17408 B
    __shared__ float Ps[NWAVE][BROWS];          // 1 KB layer-3 partials
    const int tid   = threadIdx.x;
    const int lane  = tid & 63;
    const int w     = __builtin_amdgcn_readfirstlane(tid >> 6);
    const int hg    = lane >> 5;
    const int r0    = blockIdx.x * BROWS;

    const bf16x8* wf = (const bf16x8*)g_wfrag;

    // ---- issue A-frags for layer 1 FIRST (latency hides under x staging) ----
    bf16x8 A1h[8], A1l[8];
    #pragma unroll
    for (int ks = 0; ks < 8; ++ks){
        A1h[ks] = wf[((0*8 + ks)*4 + w)*64 + lane];   // L=0,T=hi
        A1l[ks] = wf[((1*8 + ks)*4 + w)*64 + lane];   // L=0,T=lo
    }

    // ---- stage x tile: 64 rows x 128 k, split to bf16 hi/lo in LDS ----
    #pragma unroll
    for (int i = 0; i < 8; ++i){
        int idx = i*TPB + tid;            // 0..2047 float4 slots (= row*32 + kq)
        int row = idx >> 5, kq = idx & 31;
        float4 v = {0.f, 0.f, 0.f, 0.f};
        if (r0 + row < n) v = reinterpret_cast<const float4*>(node1)[(size_t)(r0+row)*32 + kq];
        ushort4 hv, lv;
        split2(v.x, hv.x, lv.x);
        split2(v.y, hv.y, lv.y);
        split2(v.z, hv.z, lv.z);
        split2(v.w, hv.w, lv.w);
        *(ushort4*)&Xh[row*XSTR + kq*4] = hv;
        *(ushort4*)&Xl[row*XSTR + kq*4] = lv;
    }

    // pin A1 in registers: opaque asm output cannot be sunk or rematerialized
    #pragma unroll
    for (int ks = 0; ks < 8; ++ks){
        asm volatile("" : "+v"(A1h[ks]), "+v"(A1l[ks]));
    }
    __syncthreads();

    f32x16 acc[2];

    // ---- layer 1 ----
    layer_compute(A1h, A1l, Xh, Xl, g_b1p, acc, lane, w);

    // ---- A-frags for layer 2: issue + pin now; latency drains under writeback ----
    bf16x8 A2h[8], A2l[8];
    #pragma unroll
    for (int ks = 0; ks < 8; ++ks){
        A2h[ks] = wf[((2*8 + ks)*4 + w)*64 + lane];   // L=1,T=hi
        A2l[ks] = wf[((3*8 + ks)*4 + w)*64 + lane];   // L=1,T=lo
    }
    #pragma unroll
    for (int ks = 0; ks < 8; ++ks){
        asm volatile("" : "+v"(A2h[ks]), "+v"(A2l[ks]));
    }

    __syncthreads();   // everyone done READING X

    // relu + bf16-split writeback: wave w writes features [32w,32w+32) for all rows
    #pragma unroll
    for (int nt = 0; nt < 2; ++nt){
        const int row = nt*32 + (lane & 31);
        #pragma unroll
        for (int qq = 0; qq < 4; ++qq){
            const int c = w*32 + qq*8 + (hg<<2);
            ushort4 hv, lv;
            float v;
            v = fmaxf(acc[nt][qq*4+0], 0.f); split2(v, hv.x, lv.x);
            v = fmaxf(acc[nt][qq*4+1], 0.f); split2(v, hv.y, lv.y);
            v = fmaxf(acc[nt][qq*4+2], 0.f); split2(v, hv.z, lv.z);
            v = fmaxf(acc[nt][qq*4+3], 0.f); split2(v, hv.w, lv.w);
            *(ushort4*)&Xh[row*XSTR + c] = hv;
            *(ushort4*)&Xl[row*XSTR + c] = lv;
        }
    }
    __syncthreads();   // h1 fully written

    // ---- layer 2 ----
    layer_compute(A2h, A2l, Xh, Xl, b2, acc, lane, w);

    // ---- layer 3: per-wave partial over its 32 features ----
    float p[2] = {0.f, 0.f};
    #pragma unroll
    for (int qq = 0; qq < 4; ++qq){
        const float4 wv = *(const float4*)&W3[w*32 + qq*8 + (hg<<2)];
        #pragma unroll
        for (int nt = 0; nt < 2; ++nt){
            p[nt] = fmaf(fmaxf(acc[nt][qq*4+0], 0.f), wv.x, p[nt]);
            p[nt] = fmaf(fmaxf(acc[nt][qq*4+1], 0.f), wv.y, p[nt]);
            p[nt] = fmaf(fmaxf(acc[nt][qq*4+2], 0.f), wv.z, p[nt]);
            p[nt] = fmaf(fmaxf(acc[nt][qq*4+3], 0.f), wv.w, p[nt]);
        }
    }
    #pragma unroll
    for (int nt = 0; nt < 2; ++nt){
        p[nt] += __shfl_xor(p[nt], 32);
        if (lane < 32) Ps[w][nt*32 + lane] = p[nt];
    }
    __syncthreads();

    // ---- cross-wave feature reduction + per-block softmax stats (wave 0) ----
    if (w == 0){
        const int ra = r0 + lane;
        const bool va = ra < n;
        const float s = Ps[0][lane] + Ps[1][lane] + Ps[2][lane] + Ps[3][lane];
        if (va) out[ra] = s;
        float m = va ? s : -3.0e38f;
        #pragma unroll
        for (int off = 32; off > 0; off >>= 1) m = fmaxf(m, __shfl_xor(m, off));
        float e = va ? expf(s - m) : 0.f;
        #pragma unroll
        for (int off = 32; off > 0; off >>= 1) e += __shfl_xor(e, off);
        if (lane == 0){ g_pm[blockIdx.x] = m; g_ps[blockIdx.x] = e; }
    }
}

__global__ __launch_bounds__(1024)
void k_combine(int ng)
{
    __shared__ float red[17];
    const int tid = threadIdx.x, lane = tid & 63, wv = tid >> 6;

    float m = -3.0e38f;
    for (int i = tid; i < ng; i += 1024) m = fmaxf(m, g_pm[i]);
    #pragma unroll
    for (int off = 32; off > 0; off >>= 1) m = fmaxf(m, __shfl_xor(m, off));
    if (lane == 0) red[wv] = m;
    __syncthreads();
    if (tid < 64){
        float v = (lane < 16) ? red[lane] : -3.0e38f;
        #pragma unroll
        for (int off = 32; off > 0; off >>= 1) v = fmaxf(v, __shfl_xor(v, off));
        if (lane == 0) red[16] = v;
    }
    __syncthreads();
    m = red[16];

    float z = 0.f;
    for (int i = tid; i < ng; i += 1024) z += g_ps[i] * expf(g_pm[i] - m);
    #pragma unroll
    for (int off = 32; off > 0; off >>= 1) z += __shfl_xor(z, off);
    __syncthreads();
    if (lane == 0) red[wv] = z;
    __syncthreads();
    if (tid < 64){
        float v = (lane < 16) ? red[lane] : 0.f;
        #pragma unroll
        for (int off = 32; off > 0; off >>= 1) v += __shfl_xor(v, off);
        if (lane == 0){ g_m = m; g_invZ = 1.0f / v; }
    }
}

__global__ __launch_bounds__(256)
void k_norm(float* __restrict__ s, int n)
{
    const int i = blockIdx.x * 256 + threadIdx.x;
    const float m = g_m, r = g_invZ;
    const int n4 = n >> 2;
    if (i < n4){
        float4 v = reinterpret_cast<float4*>(s)[i];
        v.x = expf(v.x - m) * r;
        v.y = expf(v.y - m) * r;
        v.z = expf(v.z - m) * r;
        v.w = expf(v.w - m) * r;
        reinterpret_cast<float4*>(s)[i] = v;
    }
    const int rem = n - (n4 << 2);
    if (i < rem){
        int t = (n4 << 2) + i;
        s[t] = expf(s[t] - m) * r;
    }
}

extern "C" void kernel_launch(void* const* d_in, const int* in_sizes, int n_in,
                              void* d_out, int out_size, void* d_ws, size_t ws_size,
                              hipStream_t stream)
{
    const float* node1 = (const float*)d_in[0];
    const float* urep  = (const float*)d_in[1];
    const float* W1    = (const float*)d_in[3];
    const float* b1    = (const float*)d_in[4];
    const float* W2    = (const float*)d_in[5];
    const float* b2    = (const float*)d_in[6];
    const float* W3    = (const float*)d_in[7];
    float* out = (float*)d_out;

    const int n    = in_sizes[0] / DD;            // 200000
    const int nblk = (n + BROWS - 1) / BROWS;     // 3125
    const int ng   = nblk;

    k_wprep<<<dim3(32), dim3(256), 0, stream>>>(W1, W2);
    k_b1p<<<dim3(1), dim3(128), 0, stream>>>(W1, b1, urep);
    k_mlp<<<dim3(nblk), dim3(TPB), 0, stream>>>(node1, b2, W3, out, n);
    k_combine<<<dim3(1), dim3(1024), 0, stream>>>(ng);

    const int n4  = n >> 2;
    const int nb3 = (n4 + 255) / 256 > 0 ? (n4 + 255) / 256 : 1;
    k_norm<<<dim3(nb3), dim3(256), 0, stream>>>(out, n);
}